// Round 3
// baseline (304.703 us; speedup 1.0000x reference)
//
#include <hip/hip_runtime.h>

// GCN_77584289234976 — round 3.
// R2 post-mortem: k_out 85us, all pipes <9%, VGPR_Count=64 -> pool/x loads
// serialized (latency-bound, 16 barrier phases). R3 k_out: ping-pong LDS W
// double-buffer (1 barrier/chunk), explicit register prefetch of pool+x,
// 32-node blocks (pool frags reused across 2 node tiles), bank-floor LDS
// layout [o][node][ki] (PS=1156, NS=36, b64-pair reads).
// MFMA 16x16x32 bf16 layout contract (m89/m97/m120):
//   a-frag: A[m][k], m=lane&15, k=(lane>>4)*8+j
//   b-frag: B[k][n], n=lane&15, k=(lane>>4)*8+j
//   d:      D[m][n], n(col)=lane&15, m(row)=(lane>>4)*4+reg

typedef unsigned short u16;
typedef unsigned int u32;
typedef __attribute__((ext_vector_type(8))) short bf16x8;
typedef __attribute__((ext_vector_type(4))) short bf16x4;
typedef __attribute__((ext_vector_type(4))) float f32x4;

#define NN 2048
#define EE 64
#define CC 128
#define BB 32

__device__ __forceinline__ u16 f2bf(float f) {
  u32 u = __builtin_bit_cast(u32, f);
  u += 0x7fffu + ((u >> 16) & 1u);   // round-to-nearest-even
  return (u16)(u >> 16);
}

__device__ __forceinline__ f32x4 mfma16(bf16x8 a, bf16x8 b, f32x4 c) {
  return __builtin_amdgcn_mfma_f32_16x16x32_bf16(a, b, c, 0, 0, 0);
}

// ---------------- kernel 1: e = LN(node_emb + time_emb), e_bf16, bias = e@bias_pool
__global__ __launch_bounds__(64) void k_prep(
    const float* __restrict__ ne, const float* __restrict__ te,
    const float* __restrict__ lnw, const float* __restrict__ lnb,
    const float* __restrict__ bias_pool,
    float* __restrict__ e, u16* __restrict__ e_bf, float* __restrict__ bias_out) {
  int n = blockIdx.x;
  int d = threadIdx.x;
  float v = ne[n * EE + d] + te[d];
  float s = v;
#pragma unroll
  for (int off = 32; off > 0; off >>= 1) s += __shfl_xor(s, off);
  float mean = s * (1.0f / 64.0f);
  float c = v - mean;
  float q = c * c;
#pragma unroll
  for (int off = 32; off > 0; off >>= 1) q += __shfl_xor(q, off);
  float inv = rsqrtf(q * (1.0f / 64.0f) + 1e-12f);
  float ev = c * inv * lnw[d] + lnb[d];
  e[n * EE + d] = ev;
  e_bf[n * EE + d] = f2bf(ev);
  __shared__ float sh[64];
  sh[d] = ev;
  __syncthreads();
#pragma unroll
  for (int oo = 0; oo < 2; ++oo) {
    int o = oo * 64 + d;
    float acc = 0.f;
#pragma unroll 8
    for (int dd = 0; dd < 64; ++dd) acc += sh[dd] * bias_pool[dd * CC + o];
    bias_out[n * CC + o] = acc;
  }
}

// ---------------- kernel 2: pool [d][ki][o] fp32 -> pool_r [o][ki][d] bf16
__global__ __launch_bounds__(256) void k_poolt(const float* __restrict__ pool,
                                               u16* __restrict__ pool_r) {
  __shared__ float t[128 * 65];
  int ki = blockIdx.x;
  int tid = threadIdx.x;
  for (int it = 0; it < 32; ++it) {
    int idx = it * 256 + tid;
    int d = idx >> 7, o = idx & 127;
    t[o * 65 + d] = pool[d * 32768 + ki * 128 + o];
  }
  __syncthreads();
  for (int it = 0; it < 32; ++it) {
    int idx = it * 256 + tid;
    int o = idx >> 6, d = idx & 63;
    pool_r[((size_t)o * 256 + ki) * 64 + d] = f2bf(t[o * 65 + d]);
  }
}

// ---------------- kernel 3: x fp32 [b][m][c] -> x_bf [b][m][c] bf16, x_t [b][c][m] bf16
__global__ __launch_bounds__(256) void k_xtrans(const float* __restrict__ x,
                                                u16* __restrict__ x_t,
                                                u16* __restrict__ x_bf) {
  __shared__ u16 t[128 * 68];
  int b = blockIdx.x >> 5;
  int m0 = (blockIdx.x & 31) * 64;
  int tid = threadIdx.x;
  for (int it = 0; it < 32; ++it) {
    int idx = it * 256 + tid;
    int m = idx >> 7, c = idx & 127;
    float v = x[(b * NN + m0 + m) * CC + c];
    u16 h = f2bf(v);
    x_bf[(b * NN + m0 + m) * CC + c] = h;
    t[c * 68 + m] = h;
  }
  __syncthreads();
  for (int it = 0; it < 32; ++it) {
    int idx = it * 256 + tid;
    int c = idx >> 6, m = idx & 63;
    x_t[(b * CC + c) * NN + m0 + m] = t[c * 68 + m];
  }
}

// ---------------- kernel 4: S = e @ e^T  (fp32, 128x128 tile, 8x8 per thread)
__global__ __launch_bounds__(256) void k_S(const float* __restrict__ e,
                                           float* __restrict__ S) {
  extern __shared__ float sm[];
  float* er = sm;              // [128][68]
  float* ec = sm + 128 * 68;   // [128][68]
  int n0 = (blockIdx.x >> 4) * 128, m0 = (blockIdx.x & 15) * 128;
  int tid = threadIdx.x;
  for (int it = 0; it < 32; ++it) {
    int idx = it * 256 + tid;
    int r = idx >> 6, d = idx & 63;
    er[r * 68 + d] = e[(n0 + r) * EE + d];
    ec[r * 68 + d] = e[(m0 + r) * EE + d];
  }
  __syncthreads();
  int tx = tid & 15, ty = tid >> 4;
  float acc[8][8] = {};
  for (int d4 = 0; d4 < 64; d4 += 4) {
    f32x4 av[8], bv[8];
#pragma unroll
    for (int i = 0; i < 8; ++i) av[i] = *(const f32x4*)&er[(ty + 16 * i) * 68 + d4];
#pragma unroll
    for (int j = 0; j < 8; ++j) bv[j] = *(const f32x4*)&ec[(tx + 16 * j) * 68 + d4];
#pragma unroll
    for (int i = 0; i < 8; ++i)
#pragma unroll
      for (int j = 0; j < 8; ++j) {
        acc[i][j] += av[i][0] * bv[j][0];
        acc[i][j] += av[i][1] * bv[j][1];
        acc[i][j] += av[i][2] * bv[j][2];
        acc[i][j] += av[i][3] * bv[j][3];
      }
  }
#pragma unroll
  for (int i = 0; i < 8; ++i)
#pragma unroll
    for (int j = 0; j < 8; ++j)
      S[(n0 + ty + 16 * i) * NN + m0 + tx + 16 * j] = acc[i][j];
}

// ---------------- kernel 5: adj = row-softmax(S) -> bf16
__global__ __launch_bounds__(256) void k_softmax(const float* __restrict__ S,
                                                 u16* __restrict__ adj) {
  int n = blockIdx.x;
  int tid = threadIdx.x;
  int lane = tid & 63, w = tid >> 6;
  __shared__ float red[8];
  const f32x4* Srow = (const f32x4*)(S + (size_t)n * NN);
  f32x4 v0 = Srow[tid];
  f32x4 v1 = Srow[256 + tid];
  float mx = v0[0];
#pragma unroll
  for (int k = 1; k < 4; ++k) mx = fmaxf(mx, v0[k]);
#pragma unroll
  for (int k = 0; k < 4; ++k) mx = fmaxf(mx, v1[k]);
#pragma unroll
  for (int off = 32; off > 0; off >>= 1) mx = fmaxf(mx, __shfl_xor(mx, off));
  if (lane == 0) red[w] = mx;
  __syncthreads();
  mx = fmaxf(fmaxf(red[0], red[1]), fmaxf(red[2], red[3]));
  float ex[8];
  float sum = 0.f;
#pragma unroll
  for (int k = 0; k < 4; ++k) { ex[k] = __expf(v0[k] - mx); sum += ex[k]; }
#pragma unroll
  for (int k = 0; k < 4; ++k) { ex[4 + k] = __expf(v1[k] - mx); sum += ex[4 + k]; }
#pragma unroll
  for (int off = 32; off > 0; off >>= 1) sum += __shfl_xor(sum, off);
  if (lane == 0) red[4 + w] = sum;
  __syncthreads();
  sum = red[4] + red[5] + red[6] + red[7];
  float rs = 1.0f / sum;
  u16* arow = adj + (size_t)n * NN;
  u32 p0 = (u32)f2bf(ex[0] * rs) | ((u32)f2bf(ex[1] * rs) << 16);
  u32 p1 = (u32)f2bf(ex[2] * rs) | ((u32)f2bf(ex[3] * rs) << 16);
  ((uint2*)arow)[tid] = make_uint2(p0, p1);
  p0 = (u32)f2bf(ex[4] * rs) | ((u32)f2bf(ex[5] * rs) << 16);
  p1 = (u32)f2bf(ex[6] * rs) | ((u32)f2bf(ex[7] * rs) << 16);
  ((uint2*)arow)[256 + tid] = make_uint2(p0, p1);
}

// ---------------- kernel 6: x_agg[b] = adj @ x[b]   (MFMA bf16, 128x128 block tile)
__global__ __launch_bounds__(256) void k_aggr(const u16* __restrict__ adj,
                                              const u16* __restrict__ x_t,
                                              u16* __restrict__ xagg) {
  __shared__ u16 As[128 * 72];  // [n-row][k]
  __shared__ u16 Bs[128 * 72];  // [c][k]
  int mb = blockIdx.x & 15, b = blockIdx.x >> 4;
  int n0 = mb * 128;
  int tid = threadIdx.x;
  int lane = tid & 63, w = tid >> 6;
  int wm = w >> 1, wn = w & 1;
  int lm = lane & 15, lq = lane >> 4;
  f32x4 acc[4][4] = {};
  const u16* a_src = adj + (size_t)n0 * NN;
  const u16* b_src = x_t + (size_t)b * CC * NN;
  for (int kc = 0; kc < NN; kc += 64) {
    __syncthreads();
#pragma unroll
    for (int ii = 0; ii < 4; ++ii) {
      int idx = ii * 256 + tid;
      int row = idx >> 3, ch = idx & 7;
      *(bf16x8*)&As[row * 72 + ch * 8] = *(const bf16x8*)&a_src[(size_t)row * NN + kc + ch * 8];
      *(bf16x8*)&Bs[row * 72 + ch * 8] = *(const bf16x8*)&b_src[(size_t)row * NN + kc + ch * 8];
    }
    __syncthreads();
#pragma unroll
    for (int kk = 0; kk < 64; kk += 32) {
      bf16x8 af[4], bq[4];
#pragma unroll
      for (int i = 0; i < 4; ++i)
        af[i] = *(const bf16x8*)&As[(wm * 64 + i * 16 + lm) * 72 + kk + lq * 8];
#pragma unroll
      for (int j = 0; j < 4; ++j)
        bq[j] = *(const bf16x8*)&Bs[(wn * 64 + j * 16 + lm) * 72 + kk + lq * 8];
#pragma unroll
      for (int i = 0; i < 4; ++i)
#pragma unroll
        for (int j = 0; j < 4; ++j)
          acc[i][j] = mfma16(af[i], bq[j], acc[i][j]);
    }
  }
#pragma unroll
  for (int i = 0; i < 4; ++i) {
    int nr = n0 + wm * 64 + i * 16 + lq * 4;
#pragma unroll
    for (int j = 0; j < 4; ++j) {
      int c = wn * 64 + j * 16 + lm;
#pragma unroll
      for (int r = 0; r < 4; ++r)
        xagg[((size_t)b * NN + nr + r) * CC + c] = f2bf(acc[i][j][r]);
    }
  }
}

// ---------------- kernel 7 (v3): fused W-gen + apply, ping-pong pipelined
// block: 32 nodes x 16 o, 512 threads (8 waves), 8 chunks of 32 ki.
// Wl[buf][o(16)][node(32)][ki(32)]: PS=1156 u16/o-plane, NS=36 u16/node.
//   gen writes (b64): lane lm=node -> bank step 18 (16 distinct evens), 4/bank floor.
//   apply reads (b64 pair): lane lm=o -> bank step 578%32=2, uniform 4/bank floor.
// Pipeline: gen(c+1)->buf^1 overlaps apply(c)<-buf; one barrier per chunk.
#define PS 1156
#define NS2 36
#define BS (16 * PS)
__global__ __launch_bounds__(512, 4) void k_out(const u16* __restrict__ e_bf,
                                                const u16* __restrict__ pool_r,
                                                const u16* __restrict__ x_bf,
                                                const u16* __restrict__ xagg,
                                                const float* __restrict__ bias,
                                                float* __restrict__ out) {
  __shared__ u16 Wl[2 * BS];  // 73,984 B -> 2 blocks/CU
  int og = blockIdx.x & 7, ng = blockIdx.x >> 3;
  int n0 = ng * 32, o0 = og * 16;
  int tid = threadIdx.x;
  int lane = tid & 63, w = tid >> 6;   // w in 0..7
  int lm = lane & 15, lq = lane >> 4;

  // e b-frags for 2 node tiles x 2 d-halves (persistent)
  bf16x8 eF[2][2];
#pragma unroll
  for (int nt = 0; nt < 2; ++nt)
#pragma unroll
    for (int dh = 0; dh < 2; ++dh)
      eF[nt][dh] = *(const bf16x8*)&e_bf[(n0 + nt * 16 + lm) * EE + dh * 32 + lq * 8];

  bf16x8 pf[2][2][2];  // pool prefetch [oi][kh][dh]
  auto load_pool = [&](int cc) {
#pragma unroll
    for (int oi = 0; oi < 2; ++oi)
#pragma unroll
      for (int kh = 0; kh < 2; ++kh)
#pragma unroll
        for (int dh = 0; dh < 2; ++dh)
          pf[oi][kh][dh] = *(const bf16x8*)&pool_r[
              ((size_t)(o0 + w * 2 + oi) * 256 + cc * 32 + kh * 16 + lm) * 64 + dh * 32 + lq * 8];
  };
  auto do_gen = [&](int cc) {
    int buf = cc & 1;
#pragma unroll
    for (int oi = 0; oi < 2; ++oi) {
      int o = w * 2 + oi;
#pragma unroll
      for (int kh = 0; kh < 2; ++kh)
#pragma unroll
        for (int nt = 0; nt < 2; ++nt) {
          f32x4 g = {0.f, 0.f, 0.f, 0.f};
          g = mfma16(pf[oi][kh][0], eF[nt][0], g);
          g = mfma16(pf[oi][kh][1], eF[nt][1], g);
          ushort4 h;
          h.x = f2bf(g[0]); h.y = f2bf(g[1]); h.z = f2bf(g[2]); h.w = f2bf(g[3]);
          // D: col=lm=node-within-tile, rows lq*4+r = ki-within-16
          *(ushort4*)&Wl[buf * BS + o * PS + (nt * 16 + lm) * NS2 + kh * 16 + lq * 4] = h;
        }
    }
  };

  load_pool(0);
  do_gen(0);                       // preamble: fill buf0
  f32x4 acc[4][2] = {};            // [node][batch-tile]

  for (int c = 0; c < 8; ++c) {
    int buf = c & 1;
    const u16* xs = (c < 4) ? x_bf : xagg;
    int ck = (c & 3) * 32;
    // issue x loads for apply(c)
    bf16x8 xa[4][2];
#pragma unroll
    for (int nn = 0; nn < 4; ++nn) {
      int n = n0 + w * 4 + nn;
      xa[nn][0] = *(const bf16x8*)&xs[((size_t)lm * NN + n) * CC + ck + lq * 8];
      xa[nn][1] = *(const bf16x8*)&xs[(((size_t)16 + lm) * NN + n) * CC + ck + lq * 8];
    }
    if (c < 7) load_pool(c + 1);   // pool prefetch for gen(c+1)
    __syncthreads();               // gen(c) complete for all waves
#pragma unroll
    for (int nn = 0; nn < 4; ++nn) {
      int nd = w * 4 + nn;
      int base = buf * BS + lm * PS + nd * NS2 + lq * 8;
      bf16x4 b0 = *(const bf16x4*)&Wl[base];
      bf16x4 b1 = *(const bf16x4*)&Wl[base + 4];
      bf16x8 bv = __builtin_shufflevector(b0, b1, 0, 1, 2, 3, 4, 5, 6, 7);
      acc[nn][0] = mfma16(xa[nn][0], bv, acc[nn][0]);
      acc[nn][1] = mfma16(xa[nn][1], bv, acc[nn][1]);
    }
    if (c < 7) do_gen(c + 1);      // writes buf^1: disjoint from apply reads
    // barrier at loop top next iteration covers gen(c+1)->apply(c+1) ordering;
    // need one here too so gen(c+2) (iter c+1) can't overwrite buf while
    // a slow wave still reads it — the loop-top barrier serves exactly that.
  }

  // epilogue: D col=lm -> o, rows lq*4+r -> batch within m-tile
#pragma unroll
  for (int nn = 0; nn < 4; ++nn) {
    int n = n0 + w * 4 + nn;
    int oc = o0 + lm;
    float bv = bias[n * CC + oc];
#pragma unroll
    for (int mt = 0; mt < 2; ++mt)
#pragma unroll
      for (int r = 0; r < 4; ++r) {
        int b = mt * 16 + lq * 4 + r;
        out[((size_t)b * NN + n) * CC + oc] = acc[nn][mt][r] + bv;
      }
  }
}

extern "C" void kernel_launch(void* const* d_in, const int* in_sizes, int n_in,
                              void* d_out, int out_size, void* d_ws, size_t ws_size,
                              hipStream_t stream) {
  const float* x        = (const float*)d_in[0];
  const float* node_emb = (const float*)d_in[1];
  const float* time_emb = (const float*)d_in[2];
  const float* pool     = (const float*)d_in[3];
  const float* bias_pl  = (const float*)d_in[4];
  const float* ln_w     = (const float*)d_in[5];
  const float* ln_b     = (const float*)d_in[6];
  float* out = (float*)d_out;

  char* p = (char*)d_ws;
  auto alloc = [&](size_t bytes) {
    char* r = p;
    p += (bytes + 255) & ~(size_t)255;
    return r;
  };
  float* e      = (float*)alloc((size_t)NN * EE * 4);
  u16*   e_bf   = (u16*)  alloc((size_t)NN * EE * 2);
  float* biasb  = (float*)alloc((size_t)NN * CC * 4);
  u16*   adj    = (u16*)  alloc((size_t)NN * NN * 2);
  u16*   x_t    = (u16*)  alloc((size_t)BB * CC * NN * 2);
  u16*   x_bf   = (u16*)  alloc((size_t)BB * NN * CC * 2);
  u16*   pool_r = (u16*)  alloc((size_t)128 * 256 * 64 * 2);
  char*  Sx     = alloc((size_t)NN * NN * 4);  // S fp32; later aliased by x_agg bf16
  float* S      = (float*)Sx;
  u16*   xagg   = (u16*)Sx;  // safe: S fully consumed by k_softmax before k_aggr writes

  if (ws_size < (size_t)(p - (char*)d_ws)) return;

  (void)hipFuncSetAttribute((const void*)k_S, hipFuncAttributeMaxDynamicSharedMemorySize,
                            2 * 128 * 68 * 4);

  k_prep<<<NN, 64, 0, stream>>>(node_emb, time_emb, ln_w, ln_b, bias_pl, e, e_bf, biasb);
  k_poolt<<<256, 256, 0, stream>>>(pool, pool_r);
  k_xtrans<<<BB * 32, 256, 0, stream>>>(x, x_t, x_bf);
  k_S<<<256, 256, 2 * 128 * 68 * 4, stream>>>(e, S);
  k_softmax<<<NN, 256, 0, stream>>>(S, adj);
  k_aggr<<<16 * BB, 256, 0, stream>>>(adj, x_t, xagg);
  k_out<<<512, 512, 0, stream>>>(e_bf, pool_r, x_bf, xagg, biasb, out);
}

// Round 4
// 277.684 us; speedup vs baseline: 1.0973x; 1.0973x over previous
//
#include <hip/hip_runtime.h>

// GCN_77584289234976 — round 4.
// R3 post-mortem: explicit register prefetch under (512,4) VGPR cap=128 ->
// scratch spill (hbm 553MB, WRITE 192MB). R4: (a) k_out v4: 1024 blocks
// (16n x 16o), 4 blocks/CU, 4 ki-chunks (8 barriers), no forced prefetch
// arrays, xg_t[node][batch][256] layout for cache-line-clean a-frags;
// (b) k_aggr: m97 recipe — global_load_lds width-16 staging, unpadded
// [128][64] LDS tiles, launch_bounds(256,3).
// MFMA 16x16x32 bf16 layout contract (m89/m97/m120):
//   a-frag: A[m][k], m=lane&15, k=(lane>>4)*8+j
//   b-frag: B[k][n], n=lane&15, k=(lane>>4)*8+j
//   d:      D[m][n], n(col)=lane&15, m(row)=(lane>>4)*4+reg

typedef unsigned short u16;
typedef unsigned int u32;
typedef __attribute__((ext_vector_type(8))) short bf16x8;
typedef __attribute__((ext_vector_type(4))) float f32x4;
typedef const __attribute__((address_space(1))) u16* gas1;
typedef __attribute__((address_space(3))) u16* las3;

#define NN 2048
#define EE 64
#define CC 128
#define BB 32

__device__ __forceinline__ u16 f2bf(float f) {
  u32 u = __builtin_bit_cast(u32, f);
  u += 0x7fffu + ((u >> 16) & 1u);   // round-to-nearest-even
  return (u16)(u >> 16);
}

__device__ __forceinline__ f32x4 mfma16(bf16x8 a, bf16x8 b, f32x4 c) {
  return __builtin_amdgcn_mfma_f32_16x16x32_bf16(a, b, c, 0, 0, 0);
}

// ---------------- kernel 1: e = LN(node_emb + time_emb), e_bf16, bias = e@bias_pool
__global__ __launch_bounds__(64) void k_prep(
    const float* __restrict__ ne, const float* __restrict__ te,
    const float* __restrict__ lnw, const float* __restrict__ lnb,
    const float* __restrict__ bias_pool,
    float* __restrict__ e, u16* __restrict__ e_bf, float* __restrict__ bias_out) {
  int n = blockIdx.x;
  int d = threadIdx.x;
  float v = ne[n * EE + d] + te[d];
  float s = v;
#pragma unroll
  for (int off = 32; off > 0; off >>= 1) s += __shfl_xor(s, off);
  float mean = s * (1.0f / 64.0f);
  float c = v - mean;
  float q = c * c;
#pragma unroll
  for (int off = 32; off > 0; off >>= 1) q += __shfl_xor(q, off);
  float inv = rsqrtf(q * (1.0f / 64.0f) + 1e-12f);
  float ev = c * inv * lnw[d] + lnb[d];
  e[n * EE + d] = ev;
  e_bf[n * EE + d] = f2bf(ev);
  __shared__ float sh[64];
  sh[d] = ev;
  __syncthreads();
#pragma unroll
  for (int oo = 0; oo < 2; ++oo) {
    int o = oo * 64 + d;
    float acc = 0.f;
#pragma unroll 8
    for (int dd = 0; dd < 64; ++dd) acc += sh[dd] * bias_pool[dd * CC + o];
    bias_out[n * CC + o] = acc;
  }
}

// ---------------- kernel 2: pool [d][ki][o] fp32 -> pool_r [o][ki][d] bf16
__global__ __launch_bounds__(256) void k_poolt(const float* __restrict__ pool,
                                               u16* __restrict__ pool_r) {
  __shared__ float t[128 * 65];
  int ki = blockIdx.x;
  int tid = threadIdx.x;
  for (int it = 0; it < 32; ++it) {
    int idx = it * 256 + tid;
    int d = idx >> 7, o = idx & 127;
    t[o * 65 + d] = pool[d * 32768 + ki * 128 + o];
  }
  __syncthreads();
  for (int it = 0; it < 32; ++it) {
    int idx = it * 256 + tid;
    int o = idx >> 6, d = idx & 63;
    pool_r[((size_t)o * 256 + ki) * 64 + d] = f2bf(t[o * 65 + d]);
  }
}

// ---------------- kernel 3: x fp32 [b][m][c] -> x_t [b][c][m] bf16 (k_aggr B)
//                                        and -> xg_t [m][b][0..128) bf16 (k_out A, x half)
__global__ __launch_bounds__(256) void k_xtrans(const float* __restrict__ x,
                                                u16* __restrict__ x_t,
                                                u16* __restrict__ xg_t) {
  __shared__ u16 t[128 * 68];
  int b = blockIdx.x >> 5;
  int m0 = (blockIdx.x & 31) * 64;
  int tid = threadIdx.x;
  for (int it = 0; it < 32; ++it) {
    int idx = it * 256 + tid;
    int m = idx >> 7, c = idx & 127;
    float v = x[((size_t)b * NN + m0 + m) * CC + c];
    t[c * 68 + m] = f2bf(v);
  }
  __syncthreads();
  for (int it = 0; it < 32; ++it) {
    int idx = it * 256 + tid;
    int c = idx >> 6, m = idx & 63;
    x_t[((size_t)b * CC + c) * NN + m0 + m] = t[c * 68 + m];
  }
  // xg_t lower half: [node][batch][c], c-contiguous (re-read x, L2-warm)
  for (int it = 0; it < 16; ++it) {
    int idx = it * 256 + tid;
    int m = idx >> 6, c2 = idx & 63;
    float2 v = *(const float2*)&x[((size_t)b * NN + m0 + m) * CC + c2 * 2];
    u32 pk = (u32)f2bf(v.x) | ((u32)f2bf(v.y) << 16);
    *(u32*)&xg_t[(((size_t)(m0 + m)) * 32 + b) * 256 + c2 * 2] = pk;
  }
}

// ---------------- kernel 4: S = e @ e^T  (fp32, 128x128 tile, 8x8 per thread)
__global__ __launch_bounds__(256) void k_S(const float* __restrict__ e,
                                           float* __restrict__ S) {
  extern __shared__ float sm[];
  float* er = sm;              // [128][68]
  float* ec = sm + 128 * 68;   // [128][68]
  int n0 = (blockIdx.x >> 4) * 128, m0 = (blockIdx.x & 15) * 128;
  int tid = threadIdx.x;
  for (int it = 0; it < 32; ++it) {
    int idx = it * 256 + tid;
    int r = idx >> 6, d = idx & 63;
    er[r * 68 + d] = e[(n0 + r) * EE + d];
    ec[r * 68 + d] = e[(m0 + r) * EE + d];
  }
  __syncthreads();
  int tx = tid & 15, ty = tid >> 4;
  float acc[8][8] = {};
  for (int d4 = 0; d4 < 64; d4 += 4) {
    f32x4 av[8], bv[8];
#pragma unroll
    for (int i = 0; i < 8; ++i) av[i] = *(const f32x4*)&er[(ty + 16 * i) * 68 + d4];
#pragma unroll
    for (int j = 0; j < 8; ++j) bv[j] = *(const f32x4*)&ec[(tx + 16 * j) * 68 + d4];
#pragma unroll
    for (int i = 0; i < 8; ++i)
#pragma unroll
      for (int j = 0; j < 8; ++j) {
        acc[i][j] += av[i][0] * bv[j][0];
        acc[i][j] += av[i][1] * bv[j][1];
        acc[i][j] += av[i][2] * bv[j][2];
        acc[i][j] += av[i][3] * bv[j][3];
      }
  }
#pragma unroll
  for (int i = 0; i < 8; ++i)
#pragma unroll
    for (int j = 0; j < 8; ++j)
      S[(size_t)(n0 + ty + 16 * i) * NN + m0 + tx + 16 * j] = acc[i][j];
}

// ---------------- kernel 5: adj = row-softmax(S) -> bf16
__global__ __launch_bounds__(256) void k_softmax(const float* __restrict__ S,
                                                 u16* __restrict__ adj) {
  int n = blockIdx.x;
  int tid = threadIdx.x;
  int lane = tid & 63, w = tid >> 6;
  __shared__ float red[8];
  const f32x4* Srow = (const f32x4*)(S + (size_t)n * NN);
  f32x4 v0 = Srow[tid];
  f32x4 v1 = Srow[256 + tid];
  float mx = v0[0];
#pragma unroll
  for (int k = 1; k < 4; ++k) mx = fmaxf(mx, v0[k]);
#pragma unroll
  for (int k = 0; k < 4; ++k) mx = fmaxf(mx, v1[k]);
#pragma unroll
  for (int off = 32; off > 0; off >>= 1) mx = fmaxf(mx, __shfl_xor(mx, off));
  if (lane == 0) red[w] = mx;
  __syncthreads();
  mx = fmaxf(fmaxf(red[0], red[1]), fmaxf(red[2], red[3]));
  float ex[8];
  float sum = 0.f;
#pragma unroll
  for (int k = 0; k < 4; ++k) { ex[k] = __expf(v0[k] - mx); sum += ex[k]; }
#pragma unroll
  for (int k = 0; k < 4; ++k) { ex[4 + k] = __expf(v1[k] - mx); sum += ex[4 + k]; }
#pragma unroll
  for (int off = 32; off > 0; off >>= 1) sum += __shfl_xor(sum, off);
  if (lane == 0) red[4 + w] = sum;
  __syncthreads();
  sum = red[4] + red[5] + red[6] + red[7];
  float rs = 1.0f / sum;
  u16* arow = adj + (size_t)n * NN;
  u32 p0 = (u32)f2bf(ex[0] * rs) | ((u32)f2bf(ex[1] * rs) << 16);
  u32 p1 = (u32)f2bf(ex[2] * rs) | ((u32)f2bf(ex[3] * rs) << 16);
  ((uint2*)arow)[tid] = make_uint2(p0, p1);
  p0 = (u32)f2bf(ex[4] * rs) | ((u32)f2bf(ex[5] * rs) << 16);
  p1 = (u32)f2bf(ex[6] * rs) | ((u32)f2bf(ex[7] * rs) << 16);
  ((uint2*)arow)[256 + tid] = make_uint2(p0, p1);
}

// ---------------- kernel 6: x_agg[b] = adj @ x[b]  (m97 recipe: global_load_lds,
// unpadded [128][64] tiles, BK=64). Epilogue -> xg_t upper half [node][b][128..256).
__global__ __launch_bounds__(256, 3) void k_aggr(const u16* __restrict__ adj,
                                                 const u16* __restrict__ x_t,
                                                 u16* __restrict__ xg_t) {
  __shared__ u16 As[128 * 64];  // [n-row][k] unpadded (global_load_lds contract)
  __shared__ u16 Bs[128 * 64];  // [c][k]
  int mb = blockIdx.x & 15, b = blockIdx.x >> 4;
  int n0 = mb * 128;
  int tid = threadIdx.x;
  int lane = tid & 63, w = tid >> 6;
  int wm = w >> 1, wn = w & 1;
  int lm = lane & 15, lq = lane >> 4;
  f32x4 acc[4][4] = {};
  const u16* a_src = adj + (size_t)n0 * NN;
  const u16* b_src = x_t + (size_t)b * CC * NN;
  for (int kc = 0; kc < NN; kc += 64) {
    __syncthreads();
#pragma unroll
    for (int ii = 0; ii < 4; ++ii) {
      int idx = ii * 256 + tid;
      int row = idx >> 3, ch = idx & 7;
      // LDS dest: wave-uniform base + lane*16 (m104/m108 contract); layout unpadded
      __builtin_amdgcn_global_load_lds((gas1)(a_src + (size_t)row * NN + kc + ch * 8),
                                       (las3)(As + (size_t)(ii * 256 + w * 64) * 8), 16, 0, 0);
      __builtin_amdgcn_global_load_lds((gas1)(b_src + (size_t)row * NN + kc + ch * 8),
                                       (las3)(Bs + (size_t)(ii * 256 + w * 64) * 8), 16, 0, 0);
    }
    __syncthreads();
#pragma unroll
    for (int kk = 0; kk < 64; kk += 32) {
      bf16x8 af[4], bq[4];
#pragma unroll
      for (int i = 0; i < 4; ++i)
        af[i] = *(const bf16x8*)&As[(wm * 64 + i * 16 + lm) * 64 + kk + lq * 8];
#pragma unroll
      for (int j = 0; j < 4; ++j)
        bq[j] = *(const bf16x8*)&Bs[(wn * 64 + j * 16 + lm) * 64 + kk + lq * 8];
#pragma unroll
      for (int i = 0; i < 4; ++i)
#pragma unroll
        for (int j = 0; j < 4; ++j)
          acc[i][j] = mfma16(af[i], bq[j], acc[i][j]);
    }
  }
#pragma unroll
  for (int i = 0; i < 4; ++i) {
    int nr = n0 + wm * 64 + i * 16 + lq * 4;
#pragma unroll
    for (int j = 0; j < 4; ++j) {
      int c = wn * 64 + j * 16 + lm;
#pragma unroll
      for (int r = 0; r < 4; ++r)
        xg_t[((size_t)(nr + r) * 32 + b) * 256 + 128 + c] = f2bf(acc[i][j][r]);
    }
  }
}

// ---------------- kernel 7 (v4): fused W-gen + apply
// block: 16 nodes x 16 o, 256 threads (4 waves), 4 chunks of 64 ki.
// gen: wave w -> ki-tile t=c*4+w; per o: D[m=ki16][n=node16] = pool@e^T, 2 MFMAs,
//      b64 LDS write (rows=4 consecutive ki).
// apply: wave w -> 4 nodes; A = xg_t[node][batch][ki] (cache-line clean),
//      B = W from LDS [node][o][ki] (b128, m97-profile banking).
// Wl n-stride 1040 (pad 16): write banks 4-way, read lm*64%32==0 -> 4 lq groups.
__global__ __launch_bounds__(256, 4) void k_out(const u16* __restrict__ e_bf,
                                                const u16* __restrict__ pool_r,
                                                const u16* __restrict__ xg_t,
                                                const float* __restrict__ bias,
                                                float* __restrict__ out) {
  __shared__ u16 Wl[16 * 1040];  // 33,280 B -> 4 blocks/CU
  int ng = blockIdx.x & 127, og = blockIdx.x >> 7;
  int n0 = ng * 16, o0 = og * 16;
  int tid = threadIdx.x;
  int lane = tid & 63, w = tid >> 6;   // w in 0..3
  int lm = lane & 15, lq = lane >> 4;

  bf16x8 eF0 = *(const bf16x8*)&e_bf[(n0 + lm) * EE + lq * 8];
  bf16x8 eF1 = *(const bf16x8*)&e_bf[(n0 + lm) * EE + 32 + lq * 8];
  f32x4 acc[4][2] = {};   // [node][batch-tile]

  for (int c = 0; c < 4; ++c) {
    int t = c * 4 + w;     // global 16-ki tile index for gen
    // ---- gen: 16 independent o-iterations (compiler-scheduled lookahead)
#pragma unroll 8
    for (int o = 0; o < 16; ++o) {
      const u16* ap = pool_r + ((size_t)(o0 + o) * 256 + t * 16 + lm) * 64 + lq * 8;
      bf16x8 p0 = *(const bf16x8*)ap;
      bf16x8 p1 = *(const bf16x8*)(ap + 32);
      f32x4 g = {0.f, 0.f, 0.f, 0.f};
      g = mfma16(p0, eF0, g);
      g = mfma16(p1, eF1, g);
      ushort4 h;
      h.x = f2bf(g[0]); h.y = f2bf(g[1]); h.z = f2bf(g[2]); h.w = f2bf(g[3]);
      // D: col=lm=node, rows lq*4+r = ki-local; chunk-local ki = w*16+lq*4+r
      *(ushort4*)&Wl[lm * 1040 + o * 64 + w * 16 + lq * 4] = h;
    }
    __syncthreads();
    // ---- apply: wave w -> nodes w*4..w*4+3; M=32 batch (2 tiles), N=16 o, K=64
#pragma unroll
    for (int nn = 0; nn < 4; ++nn) {
      int nd = w * 4 + nn;
      int n = n0 + nd;
#pragma unroll
      for (int ks = 0; ks < 2; ++ks) {
        int kloc = c * 64 + ks * 32 + lq * 8;
        bf16x8 a0 = *(const bf16x8*)&xg_t[((size_t)n * 32 + lm) * 256 + kloc];
        bf16x8 a1 = *(const bf16x8*)&xg_t[((size_t)n * 32 + 16 + lm) * 256 + kloc];
        bf16x8 bv = *(const bf16x8*)&Wl[nd * 1040 + lm * 64 + ks * 32 + lq * 8];
        acc[nn][0] = mfma16(a0, bv, acc[nn][0]);
        acc[nn][1] = mfma16(a1, bv, acc[nn][1]);
      }
    }
    __syncthreads();   // protect Wl reuse by gen(c+1)
  }

  // ---- epilogue: D col=lm -> o, rows lq*4+r -> batch within m-tile
#pragma unroll
  for (int nn = 0; nn < 4; ++nn) {
    int n = n0 + w * 4 + nn;
    int oc = o0 + lm;
    float bv = bias[n * CC + oc];
#pragma unroll
    for (int mt = 0; mt < 2; ++mt)
#pragma unroll
      for (int r = 0; r < 4; ++r) {
        int b = mt * 16 + lq * 4 + r;
        out[((size_t)b * NN + n) * CC + oc] = acc[nn][mt][r] + bv;
      }
  }
}

extern "C" void kernel_launch(void* const* d_in, const int* in_sizes, int n_in,
                              void* d_out, int out_size, void* d_ws, size_t ws_size,
                              hipStream_t stream) {
  const float* x        = (const float*)d_in[0];
  const float* node_emb = (const float*)d_in[1];
  const float* time_emb = (const float*)d_in[2];
  const float* pool     = (const float*)d_in[3];
  const float* bias_pl  = (const float*)d_in[4];
  const float* ln_w     = (const float*)d_in[5];
  const float* ln_b     = (const float*)d_in[6];
  float* out = (float*)d_out;

  char* p = (char*)d_ws;
  auto alloc = [&](size_t bytes) {
    char* r = p;
    p += (bytes + 255) & ~(size_t)255;
    return r;
  };
  float* e      = (float*)alloc((size_t)NN * EE * 4);
  u16*   e_bf   = (u16*)  alloc((size_t)NN * EE * 2);
  float* biasb  = (float*)alloc((size_t)NN * CC * 4);
  u16*   adj    = (u16*)  alloc((size_t)NN * NN * 2);
  u16*   x_t    = (u16*)  alloc((size_t)BB * CC * NN * 2);
  u16*   xg_t   = (u16*)  alloc((size_t)NN * BB * 256 * 2);   // [node][batch][x||xagg]
  u16*   pool_r = (u16*)  alloc((size_t)128 * 256 * 64 * 2);
  float* S      = (float*)alloc((size_t)NN * NN * 4);

  if (ws_size < (size_t)(p - (char*)d_ws)) return;

  (void)hipFuncSetAttribute((const void*)k_S, hipFuncAttributeMaxDynamicSharedMemorySize,
                            2 * 128 * 68 * 4);

  k_prep<<<NN, 64, 0, stream>>>(node_emb, time_emb, ln_w, ln_b, bias_pl, e, e_bf, biasb);
  k_poolt<<<256, 256, 0, stream>>>(pool, pool_r);
  k_xtrans<<<BB * 32, 256, 0, stream>>>(x, x_t, xg_t);
  k_S<<<256, 256, 2 * 128 * 68 * 4, stream>>>(e, S);
  k_softmax<<<NN, 256, 0, stream>>>(S, adj);
  k_aggr<<<16 * BB, 256, 0, stream>>>(adj, x_t, xg_t);
  k_out<<<8 * 128, 256, 0, stream>>>(e_bf, pool_r, xg_t, biasb, out);
}